// Round 1
// baseline (568.355 us; speedup 1.0000x reference)
//
#include <hip/hip_runtime.h>
#include <math.h>

// Problem constants
#define NTOK 8192       // B*N tokens
#define DIM 768
#define SEQ 1024
#define NH 12
#define HD 64
#define HID 3072
#define S1V 320
#define S2V 384

typedef unsigned short bfu;   // bf16 storage
typedef __attribute__((ext_vector_type(8))) short short8;
typedef __attribute__((ext_vector_type(4))) float f32x4;

__device__ __forceinline__ bfu f2bf(float f){
  unsigned int u = __float_as_uint(f);
  u += 0x7FFFu + ((u >> 16) & 1u);      // RNE
  return (bfu)(u >> 16);
}
__device__ __forceinline__ f32x4 mfma16(short8 a, short8 b, f32x4 c){
  return __builtin_amdgcn_mfma_f32_16x16x32_bf16(a, b, c, 0, 0, 0);
}
__device__ __forceinline__ void gll16(const void* g, void* l){
  __builtin_amdgcn_global_load_lds(
      (const __attribute__((address_space(1))) unsigned int*)g,
      (__attribute__((address_space(3))) unsigned int*)l, 16, 0, 0);
}
// XOR-swizzle: fold 128B-granule index bits into the 16B-slot bits.
// Involution; preserves bits [3:0] so 16B loads stay contiguous.
__device__ __forceinline__ int swz(int a){ return a ^ (((a >> 7) & 7) << 4); }

// ---------------- fp32 -> bf16 convert (weights) ----------------
__global__ __launch_bounds__(256) void cvt_kernel(const float4* __restrict__ src,
                                                  ushort4* __restrict__ dst, int n4){
  for (int i = blockIdx.x * 256 + threadIdx.x; i < n4; i += gridDim.x * 256){
    float4 f = src[i];
    ushort4 o;
    o.x = f2bf(f.x); o.y = f2bf(f.y); o.z = f2bf(f.z); o.w = f2bf(f.w);
    dst[i] = o;
  }
}

// ---------------- split LayerNorm: segments [0,320),[320,384),[384,768) ----------------
__global__ __launch_bounds__(256) void ln_split(
    const float* __restrict__ x,
    const float* __restrict__ ga, const float* __restrict__ ba,
    const float* __restrict__ gb, const float* __restrict__ bb2,
    const float* __restrict__ gc, const float* __restrict__ bc,
    bfu* __restrict__ out)
{
  const int row = blockIdx.x, t = threadIdx.x;
  const float* xr = x + (size_t)row * DIM;
  const float e0 = xr[t], e1 = xr[t + 256], e2 = xr[t + 512];
  float s0 = e0, q0 = e0 * e0, s1 = 0.f, q1 = 0.f, s2 = e2, q2 = e2 * e2;
  const int i1 = t + 256;
  if (i1 < S1V)      { s0 += e1; q0 += e1 * e1; }
  else if (i1 < S2V) { s1 += e1; q1 += e1 * e1; }
  else               { s2 += e1; q2 += e1 * e1; }
  float v[6] = {s0, q0, s1, q1, s2, q2};
  #pragma unroll
  for (int k = 0; k < 6; ++k)
    #pragma unroll
    for (int off = 32; off; off >>= 1)
      v[k] += __shfl_xor(v[k], off);
  __shared__ float red[6][4];
  const int lane = t & 63, wave = t >> 6;
  if (lane == 0){
    #pragma unroll
    for (int k = 0; k < 6; ++k) red[k][wave] = v[k];
  }
  __syncthreads();
  float tt[6];
  #pragma unroll
  for (int k = 0; k < 6; ++k) tt[k] = red[k][0] + red[k][1] + red[k][2] + red[k][3];
  const float m0 = tt[0] * (1.f/320.f);
  const float r0 = rsqrtf(tt[1] * (1.f/320.f) - m0*m0 + 1e-5f);
  const float m1 = tt[2] * (1.f/64.f);
  const float r1 = rsqrtf(tt[3] * (1.f/64.f) - m1*m1 + 1e-5f);
  const float m2 = tt[4] * (1.f/384.f);
  const float r2 = rsqrtf(tt[5] * (1.f/384.f) - m2*m2 + 1e-5f);
  bfu* orow = out + (size_t)row * DIM;
  orow[t] = f2bf((e0 - m0) * r0 * ga[t] + ba[t]);
  {
    float ov;
    if (i1 < S1V)      ov = (e1 - m0) * r0 * ga[i1] + ba[i1];
    else if (i1 < S2V) ov = (e1 - m1) * r1 * gb[i1 - S1V] + bb2[i1 - S1V];
    else               ov = (e1 - m2) * r2 * gc[i1 - S2V] + bc[i1 - S2V];
    orow[i1] = f2bf(ov);
  }
  const int i2 = t + 512;
  orow[i2] = f2bf((e2 - m2) * r2 * gc[i2 - S2V] + bc[i2 - S2V]);
}

// ---------------- bf16 GEMM: C[M,N] = A[M,K] * W[N,K]^T (both K-contiguous) ----------------
// 128x128 tile, BK=32, 4 waves (2x2), global_load_lds staging with XOR-swizzled LDS,
// T3 minimum 2-phase schedule.
template<int BIAS, int GELU_, int RESID, int OUTF32, int QSC>
__global__ __launch_bounds__(256) void gemm_bt(
    const bfu* __restrict__ A, const bfu* __restrict__ Bw,
    int N, int K, int ntn,
    const float* __restrict__ bias, const float* __restrict__ resid,
    float* __restrict__ outf, bfu* __restrict__ outb)
{
  __shared__ __align__(16) char lds[2][2][8192];
  const int tid = threadIdx.x;
  const int lane = tid & 63;
  const int wave = tid >> 6;
  const int wm = wave >> 1, wn = wave & 1;
  const int tm = blockIdx.x / ntn, tn = blockIdx.x % ntn;
  const int r = lane & 15, g = lane >> 4;

  f32x4 acc[4][4];
  #pragma unroll
  for (int i = 0; i < 4; ++i)
    #pragma unroll
    for (int j = 0; j < 4; ++j) acc[i][j] = (f32x4){0.f, 0.f, 0.f, 0.f};

  // staging: phys P covered linearly by 256 threads x 16B x 2 issues; logical L = swz(P)
  int rowS[2], colS[2], Pof[2];
  #pragma unroll
  for (int is = 0; is < 2; ++is){
    const int P = is * 4096 + tid * 16;
    const int L = swz(P);
    Pof[is] = P; rowS[is] = L >> 6; colS[is] = (L & 63) >> 1;
  }
  const bfu* Arow = A  + (size_t)tm * 128 * K;
  const bfu* Brow = Bw + (size_t)tn * 128 * K;

  // fragment read offsets (loop-invariant, swizzled)
  int offA[4], offB[4];
  #pragma unroll
  for (int f = 0; f < 4; ++f){
    offA[f] = swz((wm * 64 + f * 16 + r) * 64 + g * 16);
    offB[f] = swz((wn * 64 + f * 16 + r) * 64 + g * 16);
  }

  const int nk = K >> 5;
  #pragma unroll
  for (int is = 0; is < 2; ++is){
    gll16(Arow + (size_t)rowS[is] * K + colS[is], &lds[0][0][Pof[is]]);
    gll16(Brow + (size_t)rowS[is] * K + colS[is], &lds[0][1][Pof[is]]);
  }
  __syncthreads();

  for (int t = 0; t < nk; ++t){
    const int cur = t & 1;
    if (t + 1 < nk){
      const int k0 = (t + 1) << 5;
      #pragma unroll
      for (int is = 0; is < 2; ++is){
        gll16(Arow + (size_t)rowS[is] * K + k0 + colS[is], &lds[cur ^ 1][0][Pof[is]]);
        gll16(Brow + (size_t)rowS[is] * K + k0 + colS[is], &lds[cur ^ 1][1][Pof[is]]);
      }
    }
    const char* lA = lds[cur][0];
    const char* lB = lds[cur][1];
    short8 af[4], bfv[4];
    #pragma unroll
    for (int f = 0; f < 4; ++f){
      af[f]  = *(const short8*)(lA + offA[f]);
      bfv[f] = *(const short8*)(lB + offB[f]);
    }
    #pragma unroll
    for (int i = 0; i < 4; ++i)
      #pragma unroll
      for (int j = 0; j < 4; ++j)
        acc[i][j] = mfma16(af[i], bfv[j], acc[i][j]);
    __syncthreads();
  }

  // epilogue: C/D layout col=lane&15, row=(lane>>4)*4+reg
  const int row0 = tm * 128 + wm * 64;
  const int col0 = tn * 128 + wn * 64;
  #pragma unroll
  for (int j = 0; j < 4; ++j){
    const int colb = col0 + j * 16 + r;
    const float bi = BIAS ? bias[colb] : 0.f;
    #pragma unroll
    for (int i = 0; i < 4; ++i){
      #pragma unroll
      for (int q = 0; q < 4; ++q){
        const int rowg = row0 + i * 16 + g * 4 + q;
        float v = acc[i][j][q] + bi;
        if (GELU_) v = 0.5f * v * (1.f + erff(v * 0.70710678118654752440f));
        if (QSC && colb < 768) v *= 0.125f;   // fold attention scale into Q
        const size_t idx = (size_t)rowg * N + colb;
        if (RESID) v += resid[idx];
        if (OUTF32) outf[idx] = v;
        else        outb[idx] = f2bf(v);
      }
    }
  }
}

// ---------------- V transpose: qkv[:,1536+h*64+d] -> vt[bh][d][k] ----------------
__global__ __launch_bounds__(256) void vtrans(const bfu* __restrict__ qkv, bfu* __restrict__ vt){
  __shared__ bfu tile[64][66];
  const int bh = blockIdx.x, kt = blockIdx.y;
  const int b = bh / NH, h = bh - b * NH;
  const int tid = threadIdx.x;
  const int tr = tid >> 5;
  const int tc = (tid & 31) * 2;
  #pragma unroll
  for (int pass = 0; pass < 8; ++pass){
    const int k = pass * 8 + tr;
    const bfu* src = qkv + (size_t)(b * SEQ + kt * 64 + k) * 2304 + 1536 + h * 64 + tc;
    tile[k][tc] = src[0]; tile[k][tc + 1] = src[1];
  }
  __syncthreads();
  #pragma unroll
  for (int pass = 0; pass < 8; ++pass){
    const int d = pass * 8 + tr;
    bfu* dst = vt + ((size_t)bh * 64 + d) * SEQ + kt * 64 + tc;
    dst[0] = tile[tc][d]; dst[1] = tile[tc + 1][d];
  }
}

// ---------------- flash attention: per-wave 16 q-rows, KV tile 64 ----------------
__global__ __launch_bounds__(256) void attn(
    const bfu* __restrict__ qkv, const bfu* __restrict__ vt, bfu* __restrict__ y)
{
  __shared__ __align__(16) char plds_all[4][2048];
  const int tid = threadIdx.x, lane = tid & 63, wave = tid >> 6;
  char* plds = plds_all[wave];
  const int unit = blockIdx.x * 4 + wave;       // 6144 units
  const int bh = unit >> 6, qt = unit & 63;
  const int b = bh / NH, h = bh - b * NH;
  const int r = lane & 15, g = lane >> 4;

  const bfu* qbase = qkv + (size_t)(b * SEQ + qt * 16 + r) * 2304 + h * 64;
  short8 qf[2];
  qf[0] = *(const short8*)(qbase + g * 8);
  qf[1] = *(const short8*)(qbase + 32 + g * 8);

  const bfu* kbase = qkv + (size_t)(b * SEQ) * 2304 + 768 + h * 64 + g * 8;
  const bfu* vbase = vt + (size_t)bh * 64 * SEQ;

  float m_[4], l_[4];
  f32x4 yacc[4];
  #pragma unroll
  for (int i = 0; i < 4; ++i){ m_[i] = -1e30f; l_[i] = 0.f; yacc[i] = (f32x4){0.f,0.f,0.f,0.f}; }

  for (int kt = 0; kt < 16; ++kt){
    // S = Q K^T  (Q already scaled by 1/8 in QKV epilogue)
    f32x4 s[4];
    #pragma unroll
    for (int c = 0; c < 4; ++c){
      const bfu* kr = kbase + (size_t)(kt * 64 + c * 16 + r) * 2304;
      short8 kf0 = *(const short8*)(kr);
      short8 kf1 = *(const short8*)(kr + 32);
      s[c] = (f32x4){0.f, 0.f, 0.f, 0.f};
      s[c] = mfma16(qf[0], kf0, s[c]);
      s[c] = mfma16(qf[1], kf1, s[c]);
    }
    // row stats: row = g*4+q, cols spread across 16-lane group
    float pm[4];
    #pragma unroll
    for (int q = 0; q < 4; ++q)
      pm[q] = fmaxf(fmaxf(s[0][q], s[1][q]), fmaxf(s[2][q], s[3][q]));
    #pragma unroll
    for (int q = 0; q < 4; ++q)
      #pragma unroll
      for (int off = 1; off < 16; off <<= 1)
        pm[q] = fmaxf(pm[q], __shfl_xor(pm[q], off));
    float rs[4];
    #pragma unroll
    for (int q = 0; q < 4; ++q){
      const float mn = fmaxf(m_[q], pm[q]);
      const float al = __expf(m_[q] - mn);
      m_[q] = mn;
      l_[q] *= al;
      #pragma unroll
      for (int f = 0; f < 4; ++f) yacc[f][q] *= al;
      float acc = 0.f;
      #pragma unroll
      for (int c = 0; c < 4; ++c){
        const float p = __expf(s[c][q] - mn);
        s[c][q] = p;
        acc += p;
      }
      rs[q] = acc;
    }
    #pragma unroll
    for (int q = 0; q < 4; ++q){
      #pragma unroll
      for (int off = 1; off < 16; off <<= 1)
        rs[q] += __shfl_xor(rs[q], off);
      l_[q] += rs[q];
    }
    // P (C-layout) -> LDS (swizzled) -> A-layout
    #pragma unroll
    for (int c = 0; c < 4; ++c)
      #pragma unroll
      for (int q = 0; q < 4; ++q){
        const int a = swz((g * 4 + q) * 128 + (c * 16 + r) * 2);
        *(bfu*)&plds[a] = f2bf(s[c][q]);
      }
    short8 pa[2];
    #pragma unroll
    for (int ks = 0; ks < 2; ++ks)
      pa[ks] = *(const short8*)&plds[swz(r * 128 + ks * 64 + g * 16)];
    #pragma unroll
    for (int f = 0; f < 4; ++f){
      const bfu* vr = vbase + (size_t)(f * 16 + r) * SEQ + kt * 64 + g * 8;
      short8 vf0 = *(const short8*)(vr);
      short8 vf1 = *(const short8*)(vr + 32);
      yacc[f] = mfma16(pa[0], vf0, yacc[f]);
      yacc[f] = mfma16(pa[1], vf1, yacc[f]);
    }
  }
  bfu* yb = y + (size_t)(b * SEQ + qt * 16) * DIM + h * 64;
  #pragma unroll
  for (int f = 0; f < 4; ++f)
    #pragma unroll
    for (int q = 0; q < 4; ++q)
      yb[(size_t)(g * 4 + q) * DIM + f * 16 + r] = f2bf(yacc[f][q] / l_[q]);
}

// ---------------- launch ----------------
extern "C" void kernel_launch(void* const* d_in, const int* in_sizes, int n_in,
                              void* d_out, int out_size, void* d_ws, size_t ws_size,
                              hipStream_t stream) {
  const float* x      = (const float*)d_in[0];
  const float* ln1ag  = (const float*)d_in[1];
  const float* ln1ab  = (const float*)d_in[2];
  const float* ln1bg  = (const float*)d_in[3];
  const float* ln1bb  = (const float*)d_in[4];
  const float* ln1cg  = (const float*)d_in[5];
  const float* ln1cb  = (const float*)d_in[6];
  const float* ln2ag  = (const float*)d_in[7];
  const float* ln2ab  = (const float*)d_in[8];
  const float* ln2bg  = (const float*)d_in[9];
  const float* ln2bb  = (const float*)d_in[10];
  const float* ln2cg  = (const float*)d_in[11];
  const float* ln2cb  = (const float*)d_in[12];
  const float* qkv_w  = (const float*)d_in[13];
  const float* proj_w = (const float*)d_in[14];
  const float* proj_b = (const float*)d_in[15];
  const float* fc1_w  = (const float*)d_in[16];
  const float* fc1_b  = (const float*)d_in[17];
  const float* fc2_w  = (const float*)d_in[18];
  const float* fc2_b  = (const float*)d_in[19];
  float* outp = (float*)d_out;

  char* ws = (char*)d_ws;
  bfu* wqkv   = (bfu*)(ws + 0);            // 2304*768*2  = 3,538,944
  bfu* wproj  = (bfu*)(ws + 3538944);      //  768*768*2  = 1,179,648
  bfu* wfc1   = (bfu*)(ws + 4718592);      // 3072*768*2  = 4,718,592
  bfu* wfc2   = (bfu*)(ws + 9437184);      //  768*3072*2 = 4,718,592
  bfu* lnbuf  = (bfu*)(ws + 14155776);     // 8192*768*2  = 12,582,912
  bfu* ybuf   = (bfu*)(ws + 26738688);     // 8192*768*2  = 12,582,912
  bfu* qkvbuf = (bfu*)(ws + 39321600);     // 8192*2304*2 = 37,748,736
  bfu* vtbuf  = (bfu*)(ws + 77070336);     // 96*64*1024*2= 12,582,912  (end ~89.7MB)
  bfu* hbuf   = qkvbuf;                    // reuse qkv+vt region: 8192*3072*2 = 50,331,648

  // weights -> bf16
  cvt_kernel<<<512, 256, 0, stream>>>((const float4*)qkv_w,  (ushort4*)wqkv, 2304*768/4);
  cvt_kernel<<<256, 256, 0, stream>>>((const float4*)proj_w, (ushort4*)wproj, 768*768/4);
  cvt_kernel<<<512, 256, 0, stream>>>((const float4*)fc1_w,  (ushort4*)wfc1, 3072*768/4);
  cvt_kernel<<<512, 256, 0, stream>>>((const float4*)fc2_w,  (ushort4*)wfc2, 768*3072/4);

  // LN1
  ln_split<<<NTOK, 256, 0, stream>>>(x, ln1ag, ln1ab, ln1bg, ln1bb, ln1cg, ln1cb, lnbuf);
  // QKV (Q scaled by 0.125 in epilogue)
  gemm_bt<0,0,0,0,1><<<64*18, 256, 0, stream>>>(lnbuf, wqkv, 2304, 768, 18,
                                                nullptr, nullptr, nullptr, qkvbuf);
  // V transpose for PV B-operand
  vtrans<<<dim3(96,16), 256, 0, stream>>>(qkvbuf, vtbuf);
  // attention
  attn<<<1536, 256, 0, stream>>>(qkvbuf, vtbuf, ybuf);
  // proj + bias + residual(x) -> d_out (fp32)
  gemm_bt<1,0,1,1,0><<<64*6, 256, 0, stream>>>(ybuf, wproj, 768, 768, 6,
                                               proj_b, x, outp, nullptr);
  // LN2
  ln_split<<<NTOK, 256, 0, stream>>>(outp, ln2ag, ln2ab, ln2bg, ln2bb, ln2cg, ln2cb, lnbuf);
  // FC1 + bias + GELU -> h (bf16)
  gemm_bt<1,1,0,0,0><<<64*24, 256, 0, stream>>>(lnbuf, wfc1, 3072, 768, 24,
                                                fc1_b, nullptr, nullptr, hbuf);
  // FC2 + bias + residual(d_out) -> d_out (fp32, in-place)
  gemm_bt<1,0,1,1,0><<<64*6, 256, 0, stream>>>(hbuf, wfc2, 768, 3072, 6,
                                               fc2_b, outp, outp, nullptr);
}

// Round 2
// 454.440 us; speedup vs baseline: 1.2507x; 1.2507x over previous
//
#include <hip/hip_runtime.h>
#include <math.h>

// Problem constants
#define NTOK 8192       // B*N tokens
#define DIM 768
#define SEQ 1024
#define NH 12
#define HD 64
#define HID 3072
#define S1V 320
#define S2V 384

typedef unsigned short bfu;   // bf16 storage
typedef __attribute__((ext_vector_type(8))) short short8;
typedef __attribute__((ext_vector_type(4))) float f32x4;

__device__ __forceinline__ bfu f2bf(float f){
  unsigned int u = __float_as_uint(f);
  u += 0x7FFFu + ((u >> 16) & 1u);      // RNE
  return (bfu)(u >> 16);
}
__device__ __forceinline__ f32x4 mfma16(short8 a, short8 b, f32x4 c){
  return __builtin_amdgcn_mfma_f32_16x16x32_bf16(a, b, c, 0, 0, 0);
}
__device__ __forceinline__ void gll16(const void* g, void* l){
  __builtin_amdgcn_global_load_lds(
      (const __attribute__((address_space(1))) unsigned int*)g,
      (__attribute__((address_space(3))) unsigned int*)l, 16, 0, 0);
}
// XOR-swizzle: fold 128B-granule index bits into the 16B-slot bits.
// Involution; preserves bits [3:0] so 16B loads stay contiguous.
__device__ __forceinline__ int swz(int a){ return a ^ (((a >> 7) & 7) << 4); }

// ---------------- fp32 -> bf16 convert (weights) ----------------
__global__ __launch_bounds__(256) void cvt_kernel(const float4* __restrict__ src,
                                                  ushort4* __restrict__ dst, int n4){
  for (int i = blockIdx.x * 256 + threadIdx.x; i < n4; i += gridDim.x * 256){
    float4 f = src[i];
    ushort4 o;
    o.x = f2bf(f.x); o.y = f2bf(f.y); o.z = f2bf(f.z); o.w = f2bf(f.w);
    dst[i] = o;
  }
}

// ---------------- split LayerNorm: segments [0,320),[320,384),[384,768) ----------------
__global__ __launch_bounds__(256) void ln_split(
    const float* __restrict__ x,
    const float* __restrict__ ga, const float* __restrict__ ba,
    const float* __restrict__ gb, const float* __restrict__ bb2,
    const float* __restrict__ gc, const float* __restrict__ bc,
    bfu* __restrict__ out)
{
  const int row = blockIdx.x, t = threadIdx.x;
  const float* xr = x + (size_t)row * DIM;
  const float e0 = xr[t], e1 = xr[t + 256], e2 = xr[t + 512];
  float s0 = e0, q0 = e0 * e0, s1 = 0.f, q1 = 0.f, s2 = e2, q2 = e2 * e2;
  const int i1 = t + 256;
  if (i1 < S1V)      { s0 += e1; q0 += e1 * e1; }
  else if (i1 < S2V) { s1 += e1; q1 += e1 * e1; }
  else               { s2 += e1; q2 += e1 * e1; }
  float v[6] = {s0, q0, s1, q1, s2, q2};
  #pragma unroll
  for (int k = 0; k < 6; ++k)
    #pragma unroll
    for (int off = 32; off; off >>= 1)
      v[k] += __shfl_xor(v[k], off);
  __shared__ float red[6][4];
  const int lane = t & 63, wave = t >> 6;
  if (lane == 0){
    #pragma unroll
    for (int k = 0; k < 6; ++k) red[k][wave] = v[k];
  }
  __syncthreads();
  float tt[6];
  #pragma unroll
  for (int k = 0; k < 6; ++k) tt[k] = red[k][0] + red[k][1] + red[k][2] + red[k][3];
  const float m0 = tt[0] * (1.f/320.f);
  const float r0 = rsqrtf(tt[1] * (1.f/320.f) - m0*m0 + 1e-5f);
  const float m1 = tt[2] * (1.f/64.f);
  const float r1 = rsqrtf(tt[3] * (1.f/64.f) - m1*m1 + 1e-5f);
  const float m2 = tt[4] * (1.f/384.f);
  const float r2 = rsqrtf(tt[5] * (1.f/384.f) - m2*m2 + 1e-5f);
  bfu* orow = out + (size_t)row * DIM;
  orow[t] = f2bf((e0 - m0) * r0 * ga[t] + ba[t]);
  {
    float ov;
    if (i1 < S1V)      ov = (e1 - m0) * r0 * ga[i1] + ba[i1];
    else if (i1 < S2V) ov = (e1 - m1) * r1 * gb[i1 - S1V] + bb2[i1 - S1V];
    else               ov = (e1 - m2) * r2 * gc[i1 - S2V] + bc[i1 - S2V];
    orow[i1] = f2bf(ov);
  }
  const int i2 = t + 512;
  orow[i2] = f2bf((e2 - m2) * r2 * gc[i2 - S2V] + bc[i2 - S2V]);
}

// ---------------- bf16 GEMM: C[M,N] = A[M,K] * W[N,K]^T (both K-contiguous) ----------------
// 128x128 tile, BK=32, 4 waves (2x2), global_load_lds staging with XOR-swizzled LDS,
// T3 minimum 2-phase schedule.
template<int BIAS, int GELU_, int RESID, int OUTF32, int QSC>
__global__ __launch_bounds__(256) void gemm_bt(
    const bfu* __restrict__ A, const bfu* __restrict__ Bw,
    int N, int K, int ntn,
    const float* __restrict__ bias, const float* __restrict__ resid,
    float* __restrict__ outf, bfu* __restrict__ outb)
{
  __shared__ __align__(16) char lds[2][2][8192];
  const int tid = threadIdx.x;
  const int lane = tid & 63;
  const int wave = tid >> 6;
  const int wm = wave >> 1, wn = wave & 1;
  const int tm = blockIdx.x / ntn, tn = blockIdx.x % ntn;
  const int r = lane & 15, g = lane >> 4;

  f32x4 acc[4][4];
  #pragma unroll
  for (int i = 0; i < 4; ++i)
    #pragma unroll
    for (int j = 0; j < 4; ++j) acc[i][j] = (f32x4){0.f, 0.f, 0.f, 0.f};

  // staging: phys P covered linearly by 256 threads x 16B x 2 issues; logical L = swz(P)
  int rowS[2], colS[2], Pof[2];
  #pragma unroll
  for (int is = 0; is < 2; ++is){
    const int P = is * 4096 + tid * 16;
    const int L = swz(P);
    Pof[is] = P; rowS[is] = L >> 6; colS[is] = (L & 63) >> 1;
  }
  const bfu* Arow = A  + (size_t)tm * 128 * K;
  const bfu* Brow = Bw + (size_t)tn * 128 * K;

  // fragment read offsets (loop-invariant, swizzled)
  int offA[4], offB[4];
  #pragma unroll
  for (int f = 0; f < 4; ++f){
    offA[f] = swz((wm * 64 + f * 16 + r) * 64 + g * 16);
    offB[f] = swz((wn * 64 + f * 16 + r) * 64 + g * 16);
  }

  const int nk = K >> 5;
  #pragma unroll
  for (int is = 0; is < 2; ++is){
    gll16(Arow + (size_t)rowS[is] * K + colS[is], &lds[0][0][Pof[is]]);
    gll16(Brow + (size_t)rowS[is] * K + colS[is], &lds[0][1][Pof[is]]);
  }
  __syncthreads();

  for (int t = 0; t < nk; ++t){
    const int cur = t & 1;
    if (t + 1 < nk){
      const int k0 = (t + 1) << 5;
      #pragma unroll
      for (int is = 0; is < 2; ++is){
        gll16(Arow + (size_t)rowS[is] * K + k0 + colS[is], &lds[cur ^ 1][0][Pof[is]]);
        gll16(Brow + (size_t)rowS[is] * K + k0 + colS[is], &lds[cur ^ 1][1][Pof[is]]);
      }
    }
    const char* lA = lds[cur][0];
    const char* lB = lds[cur][1];
    short8 af[4], bfv[4];
    #pragma unroll
    for (int f = 0; f < 4; ++f){
      af[f]  = *(const short8*)(lA + offA[f]);
      bfv[f] = *(const short8*)(lB + offB[f]);
    }
    #pragma unroll
    for (int i = 0; i < 4; ++i)
      #pragma unroll
      for (int j = 0; j < 4; ++j)
        acc[i][j] = mfma16(af[i], bfv[j], acc[i][j]);
    __syncthreads();
  }

  // epilogue: C/D layout col=lane&15, row=(lane>>4)*4+reg
  const int row0 = tm * 128 + wm * 64;
  const int col0 = tn * 128 + wn * 64;
  #pragma unroll
  for (int j = 0; j < 4; ++j){
    const int colb = col0 + j * 16 + r;
    const float bi = BIAS ? bias[colb] : 0.f;
    #pragma unroll
    for (int i = 0; i < 4; ++i){
      #pragma unroll
      for (int q = 0; q < 4; ++q){
        const int rowg = row0 + i * 16 + g * 4 + q;
        float v = acc[i][j][q] + bi;
        if (GELU_) v = 0.5f * v * (1.f + erff(v * 0.70710678118654752440f));
        if (QSC && colb < 768) v *= 0.125f;   // fold attention scale into Q
        const size_t idx = (size_t)rowg * N + colb;
        if (RESID) v += resid[idx];
        if (OUTF32) outf[idx] = v;
        else        outb[idx] = f2bf(v);
      }
    }
  }
}

// ---------------- V transpose: qkv[:,1536+h*64+d] -> vt[bh][d][k] ----------------
__global__ __launch_bounds__(256) void vtrans(const bfu* __restrict__ qkv, bfu* __restrict__ vt){
  __shared__ bfu tile[64][66];
  const int bh = blockIdx.x, kt = blockIdx.y;
  const int b = bh / NH, h = bh - b * NH;
  const int tid = threadIdx.x;
  const int tr = tid >> 5;
  const int tc = (tid & 31) * 2;
  #pragma unroll
  for (int pass = 0; pass < 8; ++pass){
    const int k = pass * 8 + tr;
    const bfu* src = qkv + (size_t)(b * SEQ + kt * 64 + k) * 2304 + 1536 + h * 64 + tc;
    tile[k][tc] = src[0]; tile[k][tc + 1] = src[1];
  }
  __syncthreads();
  #pragma unroll
  for (int pass = 0; pass < 8; ++pass){
    const int d = pass * 8 + tr;
    bfu* dst = vt + ((size_t)bh * 64 + d) * SEQ + kt * 64 + tc;
    dst[0] = tile[tc][d]; dst[1] = tile[tc + 1][d];
  }
}

// ---------------- flash attention v2: 8 waves/block, LDS-staged K/V, double-buffered ----------
// Block: one (b,h), 128 q-rows (wave w owns rows q128*128 + w*16 .. +16).
// K-tile/V-tile 64x64 bf16 (8KB each) staged via global_load_lds with XOR-swizzled
// source addressing; next tile prefetched while computing current (2-phase).
__global__ __launch_bounds__(512) void attn2(
    const bfu* __restrict__ qkv, const bfu* __restrict__ vt, bfu* __restrict__ y)
{
  __shared__ __align__(16) char kbuf[2][8192];
  __shared__ __align__(16) char vbuf[2][8192];
  __shared__ __align__(16) char plds_all[8][2048];
  const int tid = threadIdx.x, lane = tid & 63, wave = tid >> 6;
  char* plds = plds_all[wave];
  const int blk = blockIdx.x;                 // 768 blocks
  const int bh = blk >> 3, q128 = blk & 7;
  const int b = bh / NH, h = bh - b * NH;
  const int r = lane & 15, g = lane >> 4;

  // Q fragments (rows q128*128 + wave*16 + r), already scaled by 1/8 in QKV epilogue
  const bfu* qbase = qkv + (size_t)(b * SEQ + q128 * 128 + wave * 16 + r) * 2304 + h * 64;
  const short8 qf0 = *(const short8*)(qbase + g * 8);
  const short8 qf1 = *(const short8*)(qbase + 32 + g * 8);

  // staging geometry: 512 threads x 16B cover one 8KB tile; logical L = swz(phys P)
  const int P = tid * 16;
  const int Ls = swz(P);
  const int srow = Ls >> 7, scol = Ls & 127;
  const char* kg = (const char*)(qkv + (size_t)(b * SEQ) * 2304 + 768 + h * 64)
                   + (size_t)srow * 4608 + scol;
  const char* vg = (const char*)(vt + (size_t)bh * 64 * SEQ)
                   + (size_t)srow * 2048 + scol;

  // fragment read offsets (identical for K and V tiles: row f*16+r, col halves)
  int off[4][2];
  #pragma unroll
  for (int f = 0; f < 4; ++f){
    off[f][0] = swz((f * 16 + r) * 128 + g * 16);
    off[f][1] = swz((f * 16 + r) * 128 + 64 + g * 16);
  }

  float m_[4], l_[4];
  f32x4 yacc[4];
  #pragma unroll
  for (int i = 0; i < 4; ++i){ m_[i] = -1e30f; l_[i] = 0.f; yacc[i] = (f32x4){0.f,0.f,0.f,0.f}; }

  // prologue: stage kt=0
  gll16(kg, &kbuf[0][P]);
  gll16(vg, &vbuf[0][P]);
  __syncthreads();

  for (int kt = 0; kt < 16; ++kt){
    const int cur = kt & 1;
    if (kt + 1 < 16){
      gll16(kg + (size_t)(kt + 1) * 294912, &kbuf[cur ^ 1][P]);   // 64 rows * 4608B
      gll16(vg + (kt + 1) * 128, &vbuf[cur ^ 1][P]);
    }
    const char* lK = kbuf[cur];
    const char* lV = vbuf[cur];

    // S = Q K^T
    f32x4 s[4];
    #pragma unroll
    for (int c = 0; c < 4; ++c){
      const short8 kf0 = *(const short8*)(lK + off[c][0]);
      const short8 kf1 = *(const short8*)(lK + off[c][1]);
      s[c] = (f32x4){0.f, 0.f, 0.f, 0.f};
      s[c] = mfma16(qf0, kf0, s[c]);
      s[c] = mfma16(qf1, kf1, s[c]);
    }
    // online softmax; row = g*4+q, cols spread across the 16-lane group
    float pm[4];
    #pragma unroll
    for (int q = 0; q < 4; ++q)
      pm[q] = fmaxf(fmaxf(s[0][q], s[1][q]), fmaxf(s[2][q], s[3][q]));
    #pragma unroll
    for (int q = 0; q < 4; ++q)
      #pragma unroll
      for (int o = 1; o < 16; o <<= 1)
        pm[q] = fmaxf(pm[q], __shfl_xor(pm[q], o));
    float rs[4];
    #pragma unroll
    for (int q = 0; q < 4; ++q){
      const float mn = fmaxf(m_[q], pm[q]);
      const float al = __expf(m_[q] - mn);
      m_[q] = mn;
      l_[q] *= al;
      #pragma unroll
      for (int f = 0; f < 4; ++f) yacc[f][q] *= al;
      float acc = 0.f;
      #pragma unroll
      for (int c = 0; c < 4; ++c){
        const float p = __expf(s[c][q] - mn);
        s[c][q] = p;
        acc += p;
      }
      rs[q] = acc;
    }
    #pragma unroll
    for (int q = 0; q < 4; ++q){
      #pragma unroll
      for (int o = 1; o < 16; o <<= 1)
        rs[q] += __shfl_xor(rs[q], o);
      l_[q] += rs[q];
    }
    // P (C-layout) -> per-wave LDS (swizzled) -> A-layout fragments
    #pragma unroll
    for (int c = 0; c < 4; ++c)
      #pragma unroll
      for (int q = 0; q < 4; ++q){
        const int a = swz((g * 4 + q) * 128 + (c * 16 + r) * 2);
        *(bfu*)&plds[a] = f2bf(s[c][q]);
      }
    short8 pa[2];
    #pragma unroll
    for (int ks = 0; ks < 2; ++ks)
      pa[ks] = *(const short8*)&plds[swz(r * 128 + ks * 64 + g * 16)];
    // y += P V
    #pragma unroll
    for (int f = 0; f < 4; ++f){
      const short8 vf0 = *(const short8*)(lV + off[f][0]);
      const short8 vf1 = *(const short8*)(lV + off[f][1]);
      yacc[f] = mfma16(pa[0], vf0, yacc[f]);
      yacc[f] = mfma16(pa[1], vf1, yacc[f]);
    }
    __syncthreads();
  }

  bfu* yb = y + (size_t)(b * SEQ + q128 * 128 + wave * 16) * DIM + h * 64;
  #pragma unroll
  for (int f = 0; f < 4; ++f)
    #pragma unroll
    for (int q = 0; q < 4; ++q)
      yb[(size_t)(g * 4 + q) * DIM + f * 16 + r] = f2bf(yacc[f][q] / l_[q]);
}

// ---------------- launch ----------------
extern "C" void kernel_launch(void* const* d_in, const int* in_sizes, int n_in,
                              void* d_out, int out_size, void* d_ws, size_t ws_size,
                              hipStream_t stream) {
  const float* x      = (const float*)d_in[0];
  const float* ln1ag  = (const float*)d_in[1];
  const float* ln1ab  = (const float*)d_in[2];
  const float* ln1bg  = (const float*)d_in[3];
  const float* ln1bb  = (const float*)d_in[4];
  const float* ln1cg  = (const float*)d_in[5];
  const float* ln1cb  = (const float*)d_in[6];
  const float* ln2ag  = (const float*)d_in[7];
  const float* ln2ab  = (const float*)d_in[8];
  const float* ln2bg  = (const float*)d_in[9];
  const float* ln2bb  = (const float*)d_in[10];
  const float* ln2cg  = (const float*)d_in[11];
  const float* ln2cb  = (const float*)d_in[12];
  const float* qkv_w  = (const float*)d_in[13];
  const float* proj_w = (const float*)d_in[14];
  const float* proj_b = (const float*)d_in[15];
  const float* fc1_w  = (const float*)d_in[16];
  const float* fc1_b  = (const float*)d_in[17];
  const float* fc2_w  = (const float*)d_in[18];
  const float* fc2_b  = (const float*)d_in[19];
  float* outp = (float*)d_out;

  char* ws = (char*)d_ws;
  bfu* wqkv   = (bfu*)(ws + 0);            // 2304*768*2  = 3,538,944
  bfu* wproj  = (bfu*)(ws + 3538944);      //  768*768*2  = 1,179,648
  bfu* wfc1   = (bfu*)(ws + 4718592);      // 3072*768*2  = 4,718,592
  bfu* wfc2   = (bfu*)(ws + 9437184);      //  768*3072*2 = 4,718,592
  bfu* lnbuf  = (bfu*)(ws + 14155776);     // 8192*768*2  = 12,582,912
  bfu* ybuf   = (bfu*)(ws + 26738688);     // 8192*768*2  = 12,582,912
  bfu* qkvbuf = (bfu*)(ws + 39321600);     // 8192*2304*2 = 37,748,736
  bfu* vtbuf  = (bfu*)(ws + 77070336);     // 96*64*1024*2= 12,582,912  (end ~89.7MB)
  bfu* hbuf   = qkvbuf;                    // reuse qkv+vt region: 8192*3072*2 = 50,331,648

  // weights -> bf16
  cvt_kernel<<<512, 256, 0, stream>>>((const float4*)qkv_w,  (ushort4*)wqkv, 2304*768/4);
  cvt_kernel<<<256, 256, 0, stream>>>((const float4*)proj_w, (ushort4*)wproj, 768*768/4);
  cvt_kernel<<<512, 256, 0, stream>>>((const float4*)fc1_w,  (ushort4*)wfc1, 3072*768/4);
  cvt_kernel<<<512, 256, 0, stream>>>((const float4*)fc2_w,  (ushort4*)wfc2, 768*3072/4);

  // LN1
  ln_split<<<NTOK, 256, 0, stream>>>(x, ln1ag, ln1ab, ln1bg, ln1bb, ln1cg, ln1cb, lnbuf);
  // QKV (Q scaled by 0.125 in epilogue)
  gemm_bt<0,0,0,0,1><<<64*18, 256, 0, stream>>>(lnbuf, wqkv, 2304, 768, 18,
                                                nullptr, nullptr, nullptr, qkvbuf);
  // V transpose for PV B-operand
  vtrans<<<dim3(96,16), 256, 0, stream>>>(qkvbuf, vtbuf);
  // attention (staged K/V, double-buffered)
  attn2<<<768, 512, 0, stream>>>(qkvbuf, vtbuf, ybuf);
  // proj + bias + residual(x) -> d_out (fp32)
  gemm_bt<1,0,1,1,0><<<64*6, 256, 0, stream>>>(ybuf, wproj, 768, 768, 6,
                                               proj_b, x, outp, nullptr);
  // LN2
  ln_split<<<NTOK, 256, 0, stream>>>(outp, ln2ag, ln2ab, ln2bg, ln2bb, ln2cg, ln2cb, lnbuf);
  // FC1 + bias + GELU -> h (bf16)
  gemm_bt<1,1,0,0,0><<<64*24, 256, 0, stream>>>(lnbuf, wfc1, 3072, 768, 24,
                                                fc1_b, nullptr, nullptr, hbuf);
  // FC2 + bias + residual(d_out) -> d_out (fp32, in-place)
  gemm_bt<1,0,1,1,0><<<64*6, 256, 0, stream>>>(hbuf, wfc2, 768, 3072, 6,
                                               fc2_b, outp, outp, nullptr);
}